// Round 2
// baseline (527.129 us; speedup 1.0000x reference)
//
#include <hip/hip_runtime.h>

typedef unsigned short u16;
typedef __attribute__((ext_vector_type(8))) short bf16x8;
typedef __attribute__((ext_vector_type(4))) float f32x4;
typedef __attribute__((ext_vector_type(8))) unsigned short u16x8;

#define T_LEN 65536
#define HID 256
#define K0 96     // IN_DIM=72 zero-padded to 96 (multiple of 32)
#define K1 256
#define BM 128
#define BN 128
#define CHUNK 64
#define NCHUNK 1024   // T_LEN / CHUNK

__device__ __forceinline__ float bf2f(u16 u) {
  unsigned x = ((unsigned)u) << 16; float f; __builtin_memcpy(&f, &x, 4); return f;
}
__device__ __forceinline__ u16 f2bf(float f) {
  unsigned x; __builtin_memcpy(&x, &f, 4);
  x += 0x7FFFu + ((x >> 16) & 1u);
  return (u16)(x >> 16);
}

__device__ __forceinline__ void gl_lds16(const void* g, void* l) {
  __builtin_amdgcn_global_load_lds((const __attribute__((address_space(1))) unsigned int*)g,
                                   (__attribute__((address_space(3))) unsigned int*)l,
                                   16, 0, 0);
}

// ---------------------------------------------------------------------------
// build x0 bf16 [T][96]: cols 0..63 = obs, 64..71 = emb[action], 72..95 = 0
// ---------------------------------------------------------------------------
__global__ __launch_bounds__(256) void build_x0(
    const float* __restrict__ obs, const int* __restrict__ act,
    const float* __restrict__ emb, u16* __restrict__ x0)
{
  const int idx = blockIdx.x * 256 + threadIdx.x;   // exactly T*24
  const int t = idx / 24, seg = idx - t * 24;
  u16 v0 = 0, v1 = 0, v2 = 0, v3 = 0;
  if (seg < 16) {
    const float4 f = *(const float4*)&obs[(size_t)t * 64 + seg * 4];
    v0 = f2bf(f.x); v1 = f2bf(f.y); v2 = f2bf(f.z); v3 = f2bf(f.w);
  } else if (seg < 18) {
    const int a = act[t];
    const int e0 = (seg - 16) * 4;
    v0 = f2bf(emb[a * 8 + e0 + 0]); v1 = f2bf(emb[a * 8 + e0 + 1]);
    v2 = f2bf(emb[a * 8 + e0 + 2]); v3 = f2bf(emb[a * 8 + e0 + 3]);
  }
  u16* p = &x0[(size_t)t * 96 + seg * 4];
  p[0] = v0; p[1] = v1; p[2] = v2; p[3] = v3;
}

// ---------------------------------------------------------------------------
// weight prep: bf16 interleaved W[4h+p][k]  (p = in/B/C/d), plus Aneg=-exp(Alog)
// ---------------------------------------------------------------------------
__global__ __launch_bounds__(256) void prep_w(
    const float* __restrict__ Win0, const float* __restrict__ WB0,
    const float* __restrict__ WC0,  const float* __restrict__ Wd0,
    const float* __restrict__ Alog0,
    const float* __restrict__ Win1, const float* __restrict__ WB1,
    const float* __restrict__ WC1,  const float* __restrict__ Wd1,
    const float* __restrict__ Alog1,
    u16* __restrict__ W0v, u16* __restrict__ W1v, float* __restrict__ Aneg)
{
  const int idx = blockIdx.x * 256 + threadIdx.x;
  if (idx < 1024 * K0) {
    const int row = idx / K0, k = idx - row * K0;
    const int h = row >> 2, p = row & 3;
    const float* W = (p == 0) ? Win0 : (p == 1) ? WB0 : (p == 2) ? WC0 : Wd0;
    W0v[idx] = f2bf((k < 72) ? W[h * 72 + k] : 0.f);
  } else if (idx < 1024 * K0 + 1024 * K1) {
    const int j = idx - 1024 * K0;
    const int row = j >> 8, k = j & 255;
    const int h = row >> 2, p = row & 3;
    const float* W = (p == 0) ? Win1 : (p == 1) ? WB1 : (p == 2) ? WC1 : Wd1;
    W1v[j] = f2bf(W[h * 256 + k]);
  } else if (idx < 1024 * K0 + 1024 * K1 + 512) {
    const int j = idx - (1024 * K0 + 1024 * K1);
    Aneg[j] = -__expf((j < 256) ? Alog0[j] : Alog1[j - 256]);
  }
}

// ---------------------------------------------------------------------------
// fused projection GEMM (bf16 MFMA) + elementwise + chunk-local scan.
// out[t][n] = sum_k X[t][k] * Wv[n][k];  Wv rows interleaved 4h+p.
// Per 64-t chunk, channel ch: writes bf16 hloc(t) (zero-seeded local state),
// apfx(t) = prod a over chunk steps <= t, c(t); fp32 chunk aggregates.
// Final h(t) = hloc(t) + apfx(t) * carry[chunk] done later in `combine`.
// ---------------------------------------------------------------------------
template <int KDIM>
__global__ __launch_bounds__(256, 3) void gemm_scan(
    const u16* __restrict__ X, const u16* __restrict__ Wv,
    const float* __restrict__ Aneg,
    u16* __restrict__ hlocb, u16* __restrict__ apfxb, u16* __restrict__ cb,
    float* __restrict__ aprod, float* __restrict__ hlast)
{
  static_assert(KDIM % 32 == 0, "K must be multiple of 32");
  __shared__ u16 sA[BM * 32];        // [128 rows][32 k] bf16
  __shared__ u16 sB[BN * 32];
  __shared__ float sT[64 * 132];     // transpose buffer, half tile, padded
  __shared__ float sAgg[8 * 32 * 2];

  const int tid = threadIdx.x;
  const int l   = tid & 63;
  const int w   = tid >> 6;          // wave 0..3
  const int n0  = blockIdx.x * BN;   // n-tiles fastest (W panel + X panel L2 reuse)
  const int m0  = blockIdx.y * BM;
  const int wm  = (w >> 1) * 64;     // wave quadrant
  const int wn  = (w & 1) * 64;

  f32x4 acc[4][4];
  const f32x4 zero = {0.f, 0.f, 0.f, 0.f};
#pragma unroll
  for (int mi = 0; mi < 4; ++mi)
#pragma unroll
    for (int ni = 0; ni < 4; ++ni) acc[mi][ni] = zero;

  // staging: per wave 2 issues of 1KB; lane lands at wave_base + l*16
  const int rr = w * 32 + (l >> 2);  // row within tile for this lane (issue adds +16)
  const int kb = (l & 3) * 16;       // byte offset within 64B k-slice

  for (int ks = 0; ks < KDIM / 32; ++ks) {
    __syncthreads();
#pragma unroll
    for (int i = 0; i < 2; ++i) {
      const char* gA = (const char*)(X + (size_t)(m0 + rr + i * 16) * KDIM + ks * 32) + kb;
      gl_lds16(gA, (char*)sA + w * 2048 + i * 1024);
      const char* gB = (const char*)(Wv + (size_t)(n0 + rr + i * 16) * KDIM + ks * 32) + kb;
      gl_lds16(gB, (char*)sB + w * 2048 + i * 1024);
    }
    __syncthreads();   // compiler emits s_waitcnt vmcnt(0) before barrier

    bf16x8 af[4], bfr[4];
#pragma unroll
    for (int mi = 0; mi < 4; ++mi)
      af[mi] = *(const bf16x8*)&sA[(wm + mi * 16 + (l & 15)) * 32 + (l >> 4) * 8];
#pragma unroll
    for (int ni = 0; ni < 4; ++ni)
      bfr[ni] = *(const bf16x8*)&sB[(wn + ni * 16 + (l & 15)) * 32 + (l >> 4) * 8];
#pragma unroll
    for (int mi = 0; mi < 4; ++mi)
#pragma unroll
      for (int ni = 0; ni < 4; ++ni)
        acc[mi][ni] = __builtin_amdgcn_mfma_f32_16x16x32_bf16(af[mi], bfr[ni], acc[mi][ni], 0, 0, 0);
  }

  // ---- epilogue: two halves of 64 t each (chunk = 64 t) ----
  const int q  = tid >> 5;           // 0..7 : 8-t sub-chunk
  const int c  = tid & 31;           // channel within block
  const int ch = (n0 >> 2) + c;      // global channel
  const float An = Aneg[ch];

  for (int hh = 0; hh < 2; ++hh) {
    __syncthreads();                 // prev iteration's sT/sAgg reads done
    if ((w >> 1) == hh) {
      // C/D layout (verified m89/m91): col = l&15 (n), row = (l>>4)*4 + v (t)
#pragma unroll
      for (int mi = 0; mi < 4; ++mi)
#pragma unroll
        for (int ni = 0; ni < 4; ++ni)
#pragma unroll
          for (int v = 0; v < 4; ++v)
            sT[(mi * 16 + (l >> 4) * 4 + v) * 132 + wn + ni * 16 + (l & 15)] = acc[mi][ni][v];
    }
    __syncthreads();

    // 8-step local scan in fp32 registers
    float Pl[8], Hl[8];
    float ap = 1.f, hl = 0.f;
#pragma unroll
    for (int j = 0; j < 8; ++j) {
      const int tl = q * 8 + j;
      const float pin = sT[tl * 132 + 4 * c + 0];
      const float pB  = sT[tl * 132 + 4 * c + 1];
      const float pC  = sT[tl * 132 + 4 * c + 2];
      const float pd  = sT[tl * 132 + 4 * c + 3];
      const float delta = 1.f / (1.f + __expf(-pd));
      const float a  = __expf(delta * An);
      hl = a * hl + pB * pin;
      ap *= a;
      Pl[j] = ap; Hl[j] = hl;
      cb[(size_t)(m0 + hh * 64 + tl) * HID + ch] = f2bf(pC);
    }
    sAgg[(q * 32 + c) * 2 + 0] = ap;
    sAgg[(q * 32 + c) * 2 + 1] = hl;
    __syncthreads();

    // combine sub-chunk aggregates: seed for this q from subchunks < q
    float sap = 1.f, shl = 0.f;
    for (int qq = 0; qq < q; ++qq) {
      const float a_ = sAgg[(qq * 32 + c) * 2 + 0];
      const float h_ = sAgg[(qq * 32 + c) * 2 + 1];
      shl = a_ * shl + h_;
      sap *= a_;
    }
#pragma unroll
    for (int j = 0; j < 8; ++j) {
      const int tl = q * 8 + j;
      const size_t r = (size_t)(m0 + hh * 64 + tl) * HID + ch;
      hlocb[r] = f2bf(Hl[j] + Pl[j] * shl);
      apfxb[r] = f2bf(Pl[j] * sap);
    }
    if (q == 7) {
      const int chunk = blockIdx.y * 2 + hh;
      aprod[(size_t)chunk * HID + ch] = sap * ap;          // full-chunk prod(a)
      hlast[(size_t)chunk * HID + ch] = Hl[7] + Pl[7] * shl; // zero-seeded h(63)
    }
  }
}

// ---------------------------------------------------------------------------
// pass2: scan chunk aggregates over 1024 chunks; carry[ck] = h before chunk ck
// 4 blocks x 64 channels, fp32 throughout
// ---------------------------------------------------------------------------
__global__ __launch_bounds__(64) void pass2(
    const float* __restrict__ aprod, const float* __restrict__ hlast,
    float* __restrict__ carry)
{
  const int h = blockIdx.x * 64 + threadIdx.x;
  float H = 0.f;
#pragma unroll 4
  for (int ck = 0; ck < NCHUNK; ++ck) {
    const size_t o = (size_t)ck * HID + h;
    carry[o] = H;
    H = aprod[o] * H + hlast[o];
  }
}

// ---------------------------------------------------------------------------
// combine: y[t][ch] = c * (hloc + apfx * carry[t/64][ch]), fully parallel
// ---------------------------------------------------------------------------
__global__ __launch_bounds__(256) void combine(
    const u16* __restrict__ hlocb, const u16* __restrict__ apfxb,
    const u16* __restrict__ cb, const float* __restrict__ carry,
    u16* __restrict__ y)
{
  const size_t v = (size_t)blockIdx.x * 256 + threadIdx.x;  // T*HID/8 vectors
  const int t   = (int)(v >> 5);
  const int ch0 = ((int)v & 31) * 8;
  const u16x8 hl8 = *(const u16x8*)&hlocb[v * 8];
  const u16x8 ap8 = *(const u16x8*)&apfxb[v * 8];
  const u16x8 c8  = *(const u16x8*)&cb[v * 8];
  const float* cr = &carry[(size_t)(t >> 6) * HID + ch0];
  const float4 cr0 = *(const float4*)&cr[0];
  const float4 cr1 = *(const float4*)&cr[4];
  const float crv[8] = {cr0.x, cr0.y, cr0.z, cr0.w, cr1.x, cr1.y, cr1.z, cr1.w};
  u16x8 o;
#pragma unroll
  for (int j = 0; j < 8; ++j)
    o[j] = f2bf(bf2f((u16)c8[j]) * (bf2f((u16)hl8[j]) + bf2f((u16)ap8[j]) * crv[j]));
  *(u16x8*)&y[v * 8] = o;
}

// ---------------------------------------------------------------------------
// head: out[t][o] = softplus(y1[t] . Wout[o] + bout[o]) + 1
// ---------------------------------------------------------------------------
__global__ __launch_bounds__(256) void head(
    const u16* __restrict__ y1, const float* __restrict__ Wout,
    const float* __restrict__ bout, float* __restrict__ out)
{
  __shared__ u16 ly[64 * 264];
  __shared__ float lw[4 * HID];
  __shared__ float lb[4];
  const int tid = threadIdx.x;
  for (int i = tid; i < 4 * HID; i += 256) lw[i] = Wout[i];
  if (tid < 4) lb[tid] = bout[tid];
  const size_t rbase = (size_t)blockIdx.x * 64 * HID;
#pragma unroll
  for (int i = 0; i < 8; ++i) {
    const int lin = i * 256 + tid;        // 2048 chunks of 8 bf16
    const int r = lin >> 5, c8 = lin & 31;
    *(u16x8*)&ly[r * 264 + c8 * 8] = *(const u16x8*)&y1[rbase + (size_t)r * HID + c8 * 8];
  }
  __syncthreads();
  const int t = tid >> 2, o = tid & 3;
  float acc = lb[o];
#pragma unroll 8
  for (int h = 0; h < HID; ++h)
    acc += bf2f(ly[t * 264 + h]) * lw[o * HID + h];
  out[((size_t)blockIdx.x * 64 + t) * 4 + o] = logf(1.f + __expf(acc)) + 1.f;
}

// ---------------------------------------------------------------------------
extern "C" void kernel_launch(void* const* d_in, const int* in_sizes, int n_in,
                              void* d_out, int out_size, void* d_ws, size_t ws_size,
                              hipStream_t stream)
{
  (void)in_sizes; (void)n_in; (void)out_size; (void)ws_size;
  const float* obs   = (const float*)d_in[0];
  const int*   act   = (const int*)d_in[1];
  const float* emb   = (const float*)d_in[2];
  const float* Win0  = (const float*)d_in[3];
  const float* WB0   = (const float*)d_in[4];
  const float* WC0   = (const float*)d_in[5];
  const float* Wd0   = (const float*)d_in[6];
  const float* Alog0 = (const float*)d_in[7];
  const float* Win1  = (const float*)d_in[8];
  const float* WB1   = (const float*)d_in[9];
  const float* WC1   = (const float*)d_in[10];
  const float* Wd1   = (const float*)d_in[11];
  const float* Alog1 = (const float*)d_in[12];
  const float* Wout  = (const float*)d_in[13];
  const float* bout  = (const float*)d_in[14];
  float* out = (float*)d_out;

  char* ws = (char*)d_ws;
  size_t off = 0;
  auto alloc = [&](size_t bytes) {
    char* p = ws + off;
    off += (bytes + 255) & ~(size_t)255;
    return p;
  };
  u16*   x0    = (u16*)  alloc((size_t)T_LEN * K0 * 2);      // 12.6 MB
  u16*   W0v   = (u16*)  alloc((size_t)1024 * K0 * 2);       // 0.2 MB
  u16*   W1v   = (u16*)  alloc((size_t)1024 * K1 * 2);       // 0.5 MB
  float* Aneg  = (float*)alloc(512 * 4);
  u16*   hlocb = (u16*)  alloc((size_t)T_LEN * HID * 2);     // 33.5 MB
  u16*   apfxb = (u16*)  alloc((size_t)T_LEN * HID * 2);     // 33.5 MB
  u16*   cb    = (u16*)  alloc((size_t)T_LEN * HID * 2);     // 33.5 MB
  u16*   y     = (u16*)  alloc((size_t)T_LEN * HID * 2);     // 33.5 MB (reused L0->L1)
  float* aprod = (float*)alloc((size_t)NCHUNK * HID * 4);    // 1 MB
  float* hlast = (float*)alloc((size_t)NCHUNK * HID * 4);    // 1 MB
  float* carry = (float*)alloc((size_t)NCHUNK * HID * 4);    // 1 MB
  // total ~150 MB

  build_x0<<<T_LEN * 24 / 256, 256, 0, stream>>>(obs, act, emb, x0);
  prep_w<<<(1024 * K0 + 1024 * K1 + 512 + 255) / 256, 256, 0, stream>>>(
      Win0, WB0, WC0, Wd0, Alog0, Win1, WB1, WC1, Wd1, Alog1, W0v, W1v, Aneg);

  // layer 0
  gemm_scan<K0><<<dim3(8, T_LEN / BM), 256, 0, stream>>>(x0, W0v, Aneg,
      hlocb, apfxb, cb, aprod, hlast);
  pass2<<<4, 64, 0, stream>>>(aprod, hlast, carry);
  combine<<<T_LEN * HID / 8 / 256, 256, 0, stream>>>(hlocb, apfxb, cb, carry, y);

  // layer 1
  gemm_scan<K1><<<dim3(8, T_LEN / BM), 256, 0, stream>>>(y, W1v, Aneg + 256,
      hlocb, apfxb, cb, aprod, hlast);
  pass2<<<4, 64, 0, stream>>>(aprod, hlast, carry);
  combine<<<T_LEN * HID / 8 / 256, 256, 0, stream>>>(hlocb, apfxb, cb, carry, y);

  // output head
  head<<<T_LEN / 64, 256, 0, stream>>>(y, Wout, bout, out);
}

// Round 4
// 294.337 us; speedup vs baseline: 1.7909x; 1.7909x over previous
//
#include <hip/hip_runtime.h>

typedef unsigned short u16;
typedef __attribute__((ext_vector_type(8))) short bf16x8;
typedef __attribute__((ext_vector_type(4))) float f32x4;
typedef __attribute__((ext_vector_type(8))) unsigned short u16x8;

#define T_LEN 65536
#define HID 256
#define K0 96     // IN_DIM=72 zero-padded to 96 (multiple of 32)
#define K1 256
#define BM 128
#define BN 128
#define CHUNK 64
#define NCHUNK 1024   // T_LEN / CHUNK
#define NSEG 32
#define CPS 32        // chunks per segment

__device__ __forceinline__ float bf2f(u16 u) {
  unsigned x = ((unsigned)u) << 16; float f; __builtin_memcpy(&f, &x, 4); return f;
}
__device__ __forceinline__ u16 f2bf(float f) {
  unsigned x; __builtin_memcpy(&x, &f, 4);
  x += 0x7FFFu + ((x >> 16) & 1u);
  return (u16)(x >> 16);
}

__device__ __forceinline__ void gl_lds16(const void* g, void* l) {
  __builtin_amdgcn_global_load_lds((const __attribute__((address_space(1))) unsigned int*)g,
                                   (__attribute__((address_space(3))) unsigned int*)l,
                                   16, 0, 0);
}

// ---------------------------------------------------------------------------
// build x0 bf16 [T][96]: cols 0..63 = obs, 64..71 = emb[action], 72..95 = 0
// ---------------------------------------------------------------------------
__global__ __launch_bounds__(256) void build_x0(
    const float* __restrict__ obs, const int* __restrict__ act,
    const float* __restrict__ emb, u16* __restrict__ x0)
{
  const int idx = blockIdx.x * 256 + threadIdx.x;   // exactly T*24
  const int t = idx / 24, seg = idx - t * 24;
  u16 v0 = 0, v1 = 0, v2 = 0, v3 = 0;
  if (seg < 16) {
    const float4 f = *(const float4*)&obs[(size_t)t * 64 + seg * 4];
    v0 = f2bf(f.x); v1 = f2bf(f.y); v2 = f2bf(f.z); v3 = f2bf(f.w);
  } else if (seg < 18) {
    const int a = act[t];
    const int e0 = (seg - 16) * 4;
    v0 = f2bf(emb[a * 8 + e0 + 0]); v1 = f2bf(emb[a * 8 + e0 + 1]);
    v2 = f2bf(emb[a * 8 + e0 + 2]); v3 = f2bf(emb[a * 8 + e0 + 3]);
  }
  u16* p = &x0[(size_t)t * 96 + seg * 4];
  p[0] = v0; p[1] = v1; p[2] = v2; p[3] = v3;
}

// ---------------------------------------------------------------------------
// weight prep: bf16 interleaved W[4h+p][k]  (p = in/B/C/d), plus Aneg=-exp(Alog)
// ---------------------------------------------------------------------------
__global__ __launch_bounds__(256) void prep_w(
    const float* __restrict__ Win0, const float* __restrict__ WB0,
    const float* __restrict__ WC0,  const float* __restrict__ Wd0,
    const float* __restrict__ Alog0,
    const float* __restrict__ Win1, const float* __restrict__ WB1,
    const float* __restrict__ WC1,  const float* __restrict__ Wd1,
    const float* __restrict__ Alog1,
    u16* __restrict__ W0v, u16* __restrict__ W1v, float* __restrict__ Aneg)
{
  const int idx = blockIdx.x * 256 + threadIdx.x;
  if (idx < 1024 * K0) {
    const int row = idx / K0, k = idx - row * K0;
    const int h = row >> 2, p = row & 3;
    const float* W = (p == 0) ? Win0 : (p == 1) ? WB0 : (p == 2) ? WC0 : Wd0;
    W0v[idx] = f2bf((k < 72) ? W[h * 72 + k] : 0.f);
  } else if (idx < 1024 * K0 + 1024 * K1) {
    const int j = idx - 1024 * K0;
    const int row = j >> 8, k = j & 255;
    const int h = row >> 2, p = row & 3;
    const float* W = (p == 0) ? Win1 : (p == 1) ? WB1 : (p == 2) ? WC1 : Wd1;
    W1v[j] = f2bf(W[h * 256 + k]);
  } else if (idx < 1024 * K0 + 1024 * K1 + 512) {
    const int j = idx - (1024 * K0 + 1024 * K1);
    Aneg[j] = -__expf((j < 256) ? Alog0[j] : Alog1[j - 256]);
  }
}

// ---------------------------------------------------------------------------
// fused projection GEMM (bf16 MFMA) + elementwise + chunk-local scan.
// out[t][n] = sum_k X[t][k] * Wv[n][k];  Wv rows interleaved 4h+p.
// Per 64-t chunk, channel ch: writes bf16 hloc(t) (zero-seeded local state),
// apfx(t) = prod a over chunk steps <= t, c(t); fp32 chunk aggregates.
// Final h(t) = hloc(t) + apfx(t) * carry[chunk] done later in `combine`.
// ---------------------------------------------------------------------------
template <int KDIM>
__global__ __launch_bounds__(256, 3) void gemm_scan(
    const u16* __restrict__ X, const u16* __restrict__ Wv,
    const float* __restrict__ Aneg,
    u16* __restrict__ hlocb, u16* __restrict__ apfxb, u16* __restrict__ cb,
    float* __restrict__ aprod, float* __restrict__ hlast)
{
  static_assert(KDIM % 32 == 0, "K must be multiple of 32");
  __shared__ u16 sA[BM * 32];        // [128 rows][32 k] bf16
  __shared__ u16 sB[BN * 32];
  __shared__ float sT[64 * 132];     // transpose buffer, half tile, padded
  __shared__ float sAgg[8 * 32 * 2];

  const int tid = threadIdx.x;
  const int l   = tid & 63;
  const int w   = tid >> 6;          // wave 0..3
  const int n0  = blockIdx.x * BN;   // n-tiles fastest (W panel + X panel L2 reuse)
  const int m0  = blockIdx.y * BM;
  const int wm  = (w >> 1) * 64;     // wave quadrant
  const int wn  = (w & 1) * 64;

  f32x4 acc[4][4];
  const f32x4 zero = {0.f, 0.f, 0.f, 0.f};
#pragma unroll
  for (int mi = 0; mi < 4; ++mi)
#pragma unroll
    for (int ni = 0; ni < 4; ++ni) acc[mi][ni] = zero;

  // staging: per wave 2 issues of 1KB; lane lands at wave_base + l*16
  const int rr = w * 32 + (l >> 2);  // row within tile for this lane (issue adds +16)
  const int kb = (l & 3) * 16;       // byte offset within 64B k-slice

  for (int ks = 0; ks < KDIM / 32; ++ks) {
    __syncthreads();
#pragma unroll
    for (int i = 0; i < 2; ++i) {
      const char* gA = (const char*)(X + (size_t)(m0 + rr + i * 16) * KDIM + ks * 32) + kb;
      gl_lds16(gA, (char*)sA + w * 2048 + i * 1024);
      const char* gB = (const char*)(Wv + (size_t)(n0 + rr + i * 16) * KDIM + ks * 32) + kb;
      gl_lds16(gB, (char*)sB + w * 2048 + i * 1024);
    }
    __syncthreads();   // compiler emits s_waitcnt vmcnt(0) before barrier

    bf16x8 af[4], bfr[4];
#pragma unroll
    for (int mi = 0; mi < 4; ++mi)
      af[mi] = *(const bf16x8*)&sA[(wm + mi * 16 + (l & 15)) * 32 + (l >> 4) * 8];
#pragma unroll
    for (int ni = 0; ni < 4; ++ni)
      bfr[ni] = *(const bf16x8*)&sB[(wn + ni * 16 + (l & 15)) * 32 + (l >> 4) * 8];
#pragma unroll
    for (int mi = 0; mi < 4; ++mi)
#pragma unroll
      for (int ni = 0; ni < 4; ++ni)
        acc[mi][ni] = __builtin_amdgcn_mfma_f32_16x16x32_bf16(af[mi], bfr[ni], acc[mi][ni], 0, 0, 0);
  }

  // ---- epilogue: two halves of 64 t each (chunk = 64 t) ----
  const int q  = tid >> 5;           // 0..7 : 8-t sub-chunk
  const int c  = tid & 31;           // channel within block
  const int ch = (n0 >> 2) + c;      // global channel
  const float An = Aneg[ch];

  for (int hh = 0; hh < 2; ++hh) {
    __syncthreads();                 // prev iteration's sT/sAgg reads done
    if ((w >> 1) == hh) {
      // C/D layout (verified m89/m91): col = l&15 (n), row = (l>>4)*4 + v (t)
#pragma unroll
      for (int mi = 0; mi < 4; ++mi)
#pragma unroll
        for (int ni = 0; ni < 4; ++ni)
#pragma unroll
          for (int v = 0; v < 4; ++v)
            sT[(mi * 16 + (l >> 4) * 4 + v) * 132 + wn + ni * 16 + (l & 15)] = acc[mi][ni][v];
    }
    __syncthreads();

    // 8-step local scan in fp32 registers
    float Pl[8], Hl[8];
    float ap = 1.f, hl = 0.f;
#pragma unroll
    for (int j = 0; j < 8; ++j) {
      const int tl = q * 8 + j;
      const float pin = sT[tl * 132 + 4 * c + 0];
      const float pB  = sT[tl * 132 + 4 * c + 1];
      const float pC  = sT[tl * 132 + 4 * c + 2];
      const float pd  = sT[tl * 132 + 4 * c + 3];
      const float delta = 1.f / (1.f + __expf(-pd));
      const float a  = __expf(delta * An);
      hl = a * hl + pB * pin;
      ap *= a;
      Pl[j] = ap; Hl[j] = hl;
      cb[(size_t)(m0 + hh * 64 + tl) * HID + ch] = f2bf(pC);
    }
    sAgg[(q * 32 + c) * 2 + 0] = ap;
    sAgg[(q * 32 + c) * 2 + 1] = hl;
    __syncthreads();

    // combine sub-chunk aggregates: seed for this q from subchunks < q
    float sap = 1.f, shl = 0.f;
    for (int qq = 0; qq < q; ++qq) {
      const float a_ = sAgg[(qq * 32 + c) * 2 + 0];
      const float h_ = sAgg[(qq * 32 + c) * 2 + 1];
      shl = a_ * shl + h_;
      sap *= a_;
    }
#pragma unroll
    for (int j = 0; j < 8; ++j) {
      const int tl = q * 8 + j;
      const size_t r = (size_t)(m0 + hh * 64 + tl) * HID + ch;
      hlocb[r] = f2bf(Hl[j] + Pl[j] * shl);
      apfxb[r] = f2bf(Pl[j] * sap);
    }
    if (q == 7) {
      const int chunk = blockIdx.y * 2 + hh;
      aprod[(size_t)chunk * HID + ch] = sap * ap;            // full-chunk prod(a)
      hlast[(size_t)chunk * HID + ch] = Hl[7] + Pl[7] * shl; // zero-seeded h(63)
    }
  }
}

// ---------------------------------------------------------------------------
// pass2a: per-segment scan of chunk aggregates (32 segments x 32 chunks)
// clocal[ck] = zero-seeded state before chunk ck within its segment
// apfxc[ck]  = prod of aprod over chunks [seg_start, ck)
// ---------------------------------------------------------------------------
__global__ __launch_bounds__(256) void pass2a(
    const float* __restrict__ aprod, const float* __restrict__ hlast,
    float* __restrict__ clocal, float* __restrict__ apfxc,
    float* __restrict__ segAP, float* __restrict__ segHL)
{
  const int s = blockIdx.x;
  const int h = threadIdx.x;
  float H = 0.f, P = 1.f;
#pragma unroll 4
  for (int j = 0; j < CPS; ++j) {
    const size_t o = (size_t)(s * CPS + j) * HID + h;
    clocal[o] = H; apfxc[o] = P;
    const float a = aprod[o], hh = hlast[o];
    H = a * H + hh;
    P *= a;
  }
  segAP[s * HID + h] = P;
  segHL[s * HID + h] = H;
}

// pass2b: scan the 32 segment aggregates -> segc[s] = global H before segment s
__global__ __launch_bounds__(256) void pass2b(
    const float* __restrict__ segAP, const float* __restrict__ segHL,
    float* __restrict__ segc)
{
  const int h = threadIdx.x;
  float S = 0.f;
#pragma unroll 4
  for (int s = 0; s < NSEG; ++s) {
    segc[s * HID + h] = S;
    S = segAP[s * HID + h] * S + segHL[s * HID + h];
  }
}

// pass2c: carry[ck] = clocal[ck] + apfxc[ck] * segc[ck/CPS]  (elementwise)
__global__ __launch_bounds__(256) void pass2c(
    const float* __restrict__ clocal, const float* __restrict__ apfxc,
    const float* __restrict__ segc, float* __restrict__ carry)
{
  const int ck = blockIdx.x;
  const int h  = threadIdx.x;
  const size_t o = (size_t)ck * HID + h;
  carry[o] = clocal[o] + apfxc[o] * segc[(ck / CPS) * HID + h];
}

// ---------------------------------------------------------------------------
// combine: y[t][ch] = c * (hloc + apfx * carry[t/64][ch]), fully parallel
// ---------------------------------------------------------------------------
__global__ __launch_bounds__(256) void combine(
    const u16* __restrict__ hlocb, const u16* __restrict__ apfxb,
    const u16* __restrict__ cb, const float* __restrict__ carry,
    u16* __restrict__ y)
{
  const size_t v = (size_t)blockIdx.x * 256 + threadIdx.x;  // T*HID/8 vectors
  const int t   = (int)(v >> 5);
  const int ch0 = ((int)v & 31) * 8;
  const u16x8 hl8 = *(const u16x8*)&hlocb[v * 8];
  const u16x8 ap8 = *(const u16x8*)&apfxb[v * 8];
  const u16x8 c8  = *(const u16x8*)&cb[v * 8];
  const float* cr = &carry[(size_t)(t >> 6) * HID + ch0];
  const float4 cr0 = *(const float4*)&cr[0];
  const float4 cr1 = *(const float4*)&cr[4];
  const float crv[8] = {cr0.x, cr0.y, cr0.z, cr0.w, cr1.x, cr1.y, cr1.z, cr1.w};
  u16x8 o;
#pragma unroll
  for (int j = 0; j < 8; ++j)
    o[j] = f2bf(bf2f((u16)c8[j]) * (bf2f((u16)hl8[j]) + bf2f((u16)ap8[j]) * crv[j]));
  *(u16x8*)&y[v * 8] = o;
}

// ---------------------------------------------------------------------------
// head: out[t][o] = softplus(y1[t] . Wout[o] + bout[o]) + 1
// ---------------------------------------------------------------------------
__global__ __launch_bounds__(256) void head(
    const u16* __restrict__ y1, const float* __restrict__ Wout,
    const float* __restrict__ bout, float* __restrict__ out)
{
  __shared__ u16 ly[64 * 264];
  __shared__ float lw[4 * HID];
  __shared__ float lb[4];
  const int tid = threadIdx.x;
  for (int i = tid; i < 4 * HID; i += 256) lw[i] = Wout[i];
  if (tid < 4) lb[tid] = bout[tid];
  const size_t rbase = (size_t)blockIdx.x * 64 * HID;
#pragma unroll
  for (int i = 0; i < 8; ++i) {
    const int lin = i * 256 + tid;        // 2048 chunks of 8 bf16
    const int r = lin >> 5, c8 = lin & 31;
    *(u16x8*)&ly[r * 264 + c8 * 8] = *(const u16x8*)&y1[rbase + (size_t)r * HID + c8 * 8];
  }
  __syncthreads();
  const int t = tid >> 2, o = tid & 3;
  float acc = lb[o];
#pragma unroll 8
  for (int h = 0; h < HID; ++h)
    acc += bf2f(ly[t * 264 + h]) * lw[o * HID + h];
  out[((size_t)blockIdx.x * 64 + t) * 4 + o] = logf(1.f + __expf(acc)) + 1.f;
}

// ---------------------------------------------------------------------------
extern "C" void kernel_launch(void* const* d_in, const int* in_sizes, int n_in,
                              void* d_out, int out_size, void* d_ws, size_t ws_size,
                              hipStream_t stream)
{
  (void)in_sizes; (void)n_in; (void)out_size; (void)ws_size;
  const float* obs   = (const float*)d_in[0];
  const int*   act   = (const int*)d_in[1];
  const float* emb   = (const float*)d_in[2];
  const float* Win0  = (const float*)d_in[3];
  const float* WB0   = (const float*)d_in[4];
  const float* WC0   = (const float*)d_in[5];
  const float* Wd0   = (const float*)d_in[6];
  const float* Alog0 = (const float*)d_in[7];
  const float* Win1  = (const float*)d_in[8];
  const float* WB1   = (const float*)d_in[9];
  const float* WC1   = (const float*)d_in[10];
  const float* Wd1   = (const float*)d_in[11];
  const float* Alog1 = (const float*)d_in[12];
  const float* Wout  = (const float*)d_in[13];
  const float* bout  = (const float*)d_in[14];
  float* out = (float*)d_out;

  char* ws = (char*)d_ws;
  size_t off = 0;
  auto alloc = [&](size_t bytes) {
    char* p = ws + off;
    off += (bytes + 255) & ~(size_t)255;
    return p;
  };
  u16*   x0    = (u16*)  alloc((size_t)T_LEN * K0 * 2);      // 12.6 MB
  u16*   W0v   = (u16*)  alloc((size_t)1024 * K0 * 2);       // 0.2 MB
  u16*   W1v   = (u16*)  alloc((size_t)1024 * K1 * 2);       // 0.5 MB
  float* Aneg  = (float*)alloc(512 * 4);
  u16*   hlocb = (u16*)  alloc((size_t)T_LEN * HID * 2);     // 33.5 MB
  u16*   apfxb = (u16*)  alloc((size_t)T_LEN * HID * 2);     // 33.5 MB
  u16*   cb    = (u16*)  alloc((size_t)T_LEN * HID * 2);     // 33.5 MB
  u16*   y     = (u16*)  alloc((size_t)T_LEN * HID * 2);     // 33.5 MB (reused L0->L1)
  float* aprod = (float*)alloc((size_t)NCHUNK * HID * 4);    // 1 MB
  float* hlast = (float*)alloc((size_t)NCHUNK * HID * 4);    // 1 MB
  float* carry = (float*)alloc((size_t)NCHUNK * HID * 4);    // 1 MB
  float* clocal= (float*)alloc((size_t)NCHUNK * HID * 4);    // 1 MB
  float* apfxc = (float*)alloc((size_t)NCHUNK * HID * 4);    // 1 MB
  float* segAP = (float*)alloc((size_t)NSEG * HID * 4);
  float* segHL = (float*)alloc((size_t)NSEG * HID * 4);
  float* segc  = (float*)alloc((size_t)NSEG * HID * 4);
  // total ~153 MB

  build_x0<<<T_LEN * 24 / 256, 256, 0, stream>>>(obs, act, emb, x0);
  prep_w<<<(1024 * K0 + 1024 * K1 + 512 + 255) / 256, 256, 0, stream>>>(
      Win0, WB0, WC0, Wd0, Alog0, Win1, WB1, WC1, Wd1, Alog1, W0v, W1v, Aneg);

  // layer 0
  gemm_scan<K0><<<dim3(8, T_LEN / BM), 256, 0, stream>>>(x0, W0v, Aneg,
      hlocb, apfxb, cb, aprod, hlast);
  pass2a<<<NSEG, 256, 0, stream>>>(aprod, hlast, clocal, apfxc, segAP, segHL);
  pass2b<<<1, 256, 0, stream>>>(segAP, segHL, segc);
  pass2c<<<NCHUNK, 256, 0, stream>>>(clocal, apfxc, segc, carry);
  combine<<<T_LEN * HID / 8 / 256, 256, 0, stream>>>(hlocb, apfxb, cb, carry, y);

  // layer 1
  gemm_scan<K1><<<dim3(8, T_LEN / BM), 256, 0, stream>>>(y, W1v, Aneg + 256,
      hlocb, apfxb, cb, aprod, hlast);
  pass2a<<<NSEG, 256, 0, stream>>>(aprod, hlast, clocal, apfxc, segAP, segHL);
  pass2b<<<1, 256, 0, stream>>>(segAP, segHL, segc);
  pass2c<<<NCHUNK, 256, 0, stream>>>(clocal, apfxc, segc, carry);
  combine<<<T_LEN * HID / 8 / 256, 256, 0, stream>>>(hlocb, apfxb, cb, carry, y);

  // output head
  head<<<T_LEN / 64, 256, 0, stream>>>(y, Wout, bout, out);
}

// Round 5
// 260.977 us; speedup vs baseline: 2.0198x; 1.1278x over previous
//
#include <hip/hip_runtime.h>

typedef unsigned short u16;
typedef __attribute__((ext_vector_type(8))) short bf16x8;
typedef __attribute__((ext_vector_type(4))) float f32x4;
typedef __attribute__((ext_vector_type(8))) unsigned short u16x8;

#define T_LEN 65536
#define HID 256
#define K0 96     // IN_DIM=72 zero-padded to 96 (multiple of 32)
#define K1 256
#define BM 128
#define BN 128
#define CHUNK 64
#define NCHUNK 1024   // T_LEN / CHUNK
#define NSEG 32
#define CPS 32        // chunks per segment

__device__ __forceinline__ float bf2f(u16 u) {
  unsigned x = ((unsigned)u) << 16; float f; __builtin_memcpy(&f, &x, 4); return f;
}
__device__ __forceinline__ u16 f2bf(float f) {
  unsigned x; __builtin_memcpy(&x, &f, 4);
  x += 0x7FFFu + ((x >> 16) & 1u);
  return (u16)(x >> 16);
}

__device__ __forceinline__ void gl_lds16(const void* g, void* l) {
  __builtin_amdgcn_global_load_lds((const __attribute__((address_space(1))) unsigned int*)g,
                                   (__attribute__((address_space(3))) unsigned int*)l,
                                   16, 0, 0);
}

// ---------------------------------------------------------------------------
// build x0 bf16 [T][96]: cols 0..63 = obs, 64..71 = emb[action], 72..95 = 0
// ---------------------------------------------------------------------------
__global__ __launch_bounds__(256) void build_x0(
    const float* __restrict__ obs, const int* __restrict__ act,
    const float* __restrict__ emb, u16* __restrict__ x0)
{
  const int idx = blockIdx.x * 256 + threadIdx.x;   // exactly T*24
  const int t = idx / 24, seg = idx - t * 24;
  u16 v0 = 0, v1 = 0, v2 = 0, v3 = 0;
  if (seg < 16) {
    const float4 f = *(const float4*)&obs[(size_t)t * 64 + seg * 4];
    v0 = f2bf(f.x); v1 = f2bf(f.y); v2 = f2bf(f.z); v3 = f2bf(f.w);
  } else if (seg < 18) {
    const int a = act[t];
    const int e0 = (seg - 16) * 4;
    v0 = f2bf(emb[a * 8 + e0 + 0]); v1 = f2bf(emb[a * 8 + e0 + 1]);
    v2 = f2bf(emb[a * 8 + e0 + 2]); v3 = f2bf(emb[a * 8 + e0 + 3]);
  }
  u16* p = &x0[(size_t)t * 96 + seg * 4];
  p[0] = v0; p[1] = v1; p[2] = v2; p[3] = v3;
}

// ---------------------------------------------------------------------------
// weight prep: bf16 interleaved W[4h+p][k]  (p = in/B/C/d), plus Aneg=-exp(Alog)
// ---------------------------------------------------------------------------
__global__ __launch_bounds__(256) void prep_w(
    const float* __restrict__ Win0, const float* __restrict__ WB0,
    const float* __restrict__ WC0,  const float* __restrict__ Wd0,
    const float* __restrict__ Alog0,
    const float* __restrict__ Win1, const float* __restrict__ WB1,
    const float* __restrict__ WC1,  const float* __restrict__ Wd1,
    const float* __restrict__ Alog1,
    u16* __restrict__ W0v, u16* __restrict__ W1v, float* __restrict__ Aneg)
{
  const int idx = blockIdx.x * 256 + threadIdx.x;
  if (idx < 1024 * K0) {
    const int row = idx / K0, k = idx - row * K0;
    const int h = row >> 2, p = row & 3;
    const float* W = (p == 0) ? Win0 : (p == 1) ? WB0 : (p == 2) ? WC0 : Wd0;
    W0v[idx] = f2bf((k < 72) ? W[h * 72 + k] : 0.f);
  } else if (idx < 1024 * K0 + 1024 * K1) {
    const int j = idx - 1024 * K0;
    const int row = j >> 8, k = j & 255;
    const int h = row >> 2, p = row & 3;
    const float* W = (p == 0) ? Win1 : (p == 1) ? WB1 : (p == 2) ? WC1 : Wd1;
    W1v[j] = f2bf(W[h * 256 + k]);
  } else if (idx < 1024 * K0 + 1024 * K1 + 512) {
    const int j = idx - (1024 * K0 + 1024 * K1);
    Aneg[j] = -__expf((j < 256) ? Alog0[j] : Alog1[j - 256]);
  }
}

// ---------------------------------------------------------------------------
// fused projection GEMM (bf16 MFMA) + elementwise + chunk-local scan.
// out[t][n] = sum_k X[t][k] * Wv[n][k];  Wv rows interleaved 4h+p.
// Per 64-t chunk, channel ch: stores ONE packed u32 per (t,ch):
//   low16  = bf16( c(t) * hloc(t) )   (zero-seeded local state scaled by C)
//   high16 = bf16( c(t) * apfx(t) )   (prefix prod of a scaled by C)
// so that y(t) = u + v * carry[chunk] later. fp32 chunk aggregates.
// XCD-aware block decode: bid%8 = XCD (dispatch round-robin); each XCD owns
// 64 consecutive m-tiles, and the 8 n-blocks of one m-tile run consecutively
// on that XCD -> X panel fetched by exactly one per-XCD L2.
// ---------------------------------------------------------------------------
template <int KDIM>
__global__ __launch_bounds__(256, 3) void gemm_scan(
    const u16* __restrict__ X, const u16* __restrict__ Wv,
    const float* __restrict__ Aneg,
    unsigned* __restrict__ uvb,
    float* __restrict__ aprod, float* __restrict__ hlast)
{
  static_assert(KDIM % 32 == 0, "K must be multiple of 32");
  __shared__ u16 sA[BM * 32];        // [128 rows][32 k] bf16
  __shared__ u16 sB[BN * 32];
  __shared__ float sT[64 * 132];     // transpose buffer, half tile, padded
  __shared__ float sAgg[8 * 32 * 2];

  const int tid = threadIdx.x;
  const int l   = tid & 63;
  const int w   = tid >> 6;          // wave 0..3
  const int bid = blockIdx.x;        // 4096 = 512 m-tiles x 8 n-tiles
  const int xcd = bid & 7;
  const int k_  = bid >> 3;          // 0..511 within this XCD's share
  const int mt  = xcd * 64 + (k_ >> 3);  // m-tile 0..511
  const int nt  = k_ & 7;                // n-tile 0..7
  const int m0  = mt * BM;
  const int n0  = nt * BN;
  const int wm  = (w >> 1) * 64;     // wave quadrant
  const int wn  = (w & 1) * 64;

  f32x4 acc[4][4];
  const f32x4 zero = {0.f, 0.f, 0.f, 0.f};
#pragma unroll
  for (int mi = 0; mi < 4; ++mi)
#pragma unroll
    for (int ni = 0; ni < 4; ++ni) acc[mi][ni] = zero;

  // staging: per wave 2 issues of 1KB; lane lands at wave_base + l*16
  const int rr = w * 32 + (l >> 2);  // row within tile for this lane (issue adds +16)
  const int kb = (l & 3) * 16;       // byte offset within 64B k-slice

  for (int ks = 0; ks < KDIM / 32; ++ks) {
    __syncthreads();
#pragma unroll
    for (int i = 0; i < 2; ++i) {
      const char* gA = (const char*)(X + (size_t)(m0 + rr + i * 16) * KDIM + ks * 32) + kb;
      gl_lds16(gA, (char*)sA + w * 2048 + i * 1024);
      const char* gB = (const char*)(Wv + (size_t)(n0 + rr + i * 16) * KDIM + ks * 32) + kb;
      gl_lds16(gB, (char*)sB + w * 2048 + i * 1024);
    }
    __syncthreads();   // compiler emits s_waitcnt vmcnt(0) before barrier

    bf16x8 af[4], bfr[4];
#pragma unroll
    for (int mi = 0; mi < 4; ++mi)
      af[mi] = *(const bf16x8*)&sA[(wm + mi * 16 + (l & 15)) * 32 + (l >> 4) * 8];
#pragma unroll
    for (int ni = 0; ni < 4; ++ni)
      bfr[ni] = *(const bf16x8*)&sB[(wn + ni * 16 + (l & 15)) * 32 + (l >> 4) * 8];
#pragma unroll
    for (int mi = 0; mi < 4; ++mi)
#pragma unroll
      for (int ni = 0; ni < 4; ++ni)
        acc[mi][ni] = __builtin_amdgcn_mfma_f32_16x16x32_bf16(af[mi], bfr[ni], acc[mi][ni], 0, 0, 0);
  }

  // ---- epilogue: two halves of 64 t each (chunk = 64 t) ----
  const int q  = tid >> 5;           // 0..7 : 8-t sub-chunk
  const int c  = tid & 31;           // channel within block
  const int ch = (n0 >> 2) + c;      // global channel
  const float An = Aneg[ch];

  for (int hh = 0; hh < 2; ++hh) {
    __syncthreads();                 // prev iteration's sT/sAgg reads done
    if ((w >> 1) == hh) {
      // C/D layout (verified m89/m91): col = l&15 (n), row = (l>>4)*4 + v (t)
#pragma unroll
      for (int mi = 0; mi < 4; ++mi)
#pragma unroll
        for (int ni = 0; ni < 4; ++ni)
#pragma unroll
          for (int v = 0; v < 4; ++v)
            sT[(mi * 16 + (l >> 4) * 4 + v) * 132 + wn + ni * 16 + (l & 15)] = acc[mi][ni][v];
    }
    __syncthreads();

    // 8-step local scan in fp32 registers
    float Pl[8], Hl[8], Cl[8];
    float ap = 1.f, hl = 0.f;
#pragma unroll
    for (int j = 0; j < 8; ++j) {
      const int tl = q * 8 + j;
      const float pin = sT[tl * 132 + 4 * c + 0];
      const float pB  = sT[tl * 132 + 4 * c + 1];
      const float pC  = sT[tl * 132 + 4 * c + 2];
      const float pd  = sT[tl * 132 + 4 * c + 3];
      const float delta = 1.f / (1.f + __expf(-pd));
      const float a  = __expf(delta * An);
      hl = a * hl + pB * pin;
      ap *= a;
      Pl[j] = ap; Hl[j] = hl; Cl[j] = pC;
    }
    sAgg[(q * 32 + c) * 2 + 0] = ap;
    sAgg[(q * 32 + c) * 2 + 1] = hl;
    __syncthreads();

    // combine sub-chunk aggregates: seed for this q from subchunks < q
    float sap = 1.f, shl = 0.f;
    for (int qq = 0; qq < q; ++qq) {
      const float a_ = sAgg[(qq * 32 + c) * 2 + 0];
      const float h_ = sAgg[(qq * 32 + c) * 2 + 1];
      shl = a_ * shl + h_;
      sap *= a_;
    }
#pragma unroll
    for (int j = 0; j < 8; ++j) {
      const int tl = q * 8 + j;
      const float hloc = Hl[j] + Pl[j] * shl;     // zero-seeded local state
      const float vpfx = Pl[j] * sap;             // chunk prefix prod
      const unsigned pack = (unsigned)f2bf(Cl[j] * hloc)
                          | ((unsigned)f2bf(Cl[j] * vpfx) << 16);
      uvb[(size_t)(m0 + hh * 64 + tl) * HID + ch] = pack;
    }
    if (q == 7) {
      const int chunk = mt * 2 + hh;
      aprod[(size_t)chunk * HID + ch] = sap * ap;            // full-chunk prod(a)
      hlast[(size_t)chunk * HID + ch] = Hl[7] + Pl[7] * shl; // zero-seeded h(63)
    }
  }
}

// ---------------------------------------------------------------------------
// pass2a: per-segment scan of chunk aggregates (32 segments x 32 chunks)
// clocal[ck] = zero-seeded state before chunk ck within its segment
// apfxc[ck]  = prod of aprod over chunks [seg_start, ck)
// ---------------------------------------------------------------------------
__global__ __launch_bounds__(256) void pass2a(
    const float* __restrict__ aprod, const float* __restrict__ hlast,
    float* __restrict__ clocal, float* __restrict__ apfxc,
    float* __restrict__ segAP, float* __restrict__ segHL)
{
  const int s = blockIdx.x;
  const int h = threadIdx.x;
  float H = 0.f, P = 1.f;
#pragma unroll 4
  for (int j = 0; j < CPS; ++j) {
    const size_t o = (size_t)(s * CPS + j) * HID + h;
    clocal[o] = H; apfxc[o] = P;
    const float a = aprod[o], hh = hlast[o];
    H = a * H + hh;
    P *= a;
  }
  segAP[s * HID + h] = P;
  segHL[s * HID + h] = H;
}

// pass2b: scan the 32 segment aggregates -> segc[s] = global H before segment s
__global__ __launch_bounds__(256) void pass2b(
    const float* __restrict__ segAP, const float* __restrict__ segHL,
    float* __restrict__ segc)
{
  const int h = threadIdx.x;
  float S = 0.f;
#pragma unroll 4
  for (int s = 0; s < NSEG; ++s) {
    segc[s * HID + h] = S;
    S = segAP[s * HID + h] * S + segHL[s * HID + h];
  }
}

// ---------------------------------------------------------------------------
// combine: y[t][ch] = u + v * carry,  carry = clocal + apfxc * segc (fused
// pass2c; those arrays are ~1 MB, L2-resident). uvb packs (u,v) as 2x bf16.
// ---------------------------------------------------------------------------
__global__ __launch_bounds__(256) void combine(
    const unsigned* __restrict__ uvb,
    const float* __restrict__ clocal, const float* __restrict__ apfxc,
    const float* __restrict__ segc, u16* __restrict__ y)
{
  const size_t vi = (size_t)blockIdx.x * 256 + threadIdx.x;  // T*HID/8 vectors
  const int t   = (int)(vi >> 5);
  const int ch0 = ((int)vi & 31) * 8;
  const int ck  = t >> 6;
  const int sg  = ck / CPS;
  const float* cl = &clocal[(size_t)ck * HID + ch0];
  const float* ax = &apfxc[(size_t)ck * HID + ch0];
  const float* sc = &segc[(size_t)sg * HID + ch0];
  const float4 cl0 = *(const float4*)&cl[0], cl1 = *(const float4*)&cl[4];
  const float4 ax0 = *(const float4*)&ax[0], ax1 = *(const float4*)&ax[4];
  const float4 sc0 = *(const float4*)&sc[0], sc1 = *(const float4*)&sc[4];
  const float crv[8] = {
    cl0.x + ax0.x * sc0.x, cl0.y + ax0.y * sc0.y,
    cl0.z + ax0.z * sc0.z, cl0.w + ax0.w * sc0.w,
    cl1.x + ax1.x * sc1.x, cl1.y + ax1.y * sc1.y,
    cl1.z + ax1.z * sc1.z, cl1.w + ax1.w * sc1.w };
  const uint4 p0 = *(const uint4*)&uvb[vi * 8];
  const uint4 p1 = *(const uint4*)&uvb[vi * 8 + 4];
  const unsigned pk[8] = {p0.x, p0.y, p0.z, p0.w, p1.x, p1.y, p1.z, p1.w};
  u16x8 o;
#pragma unroll
  for (int j = 0; j < 8; ++j)
    o[j] = f2bf(bf2f((u16)(pk[j] & 0xffffu)) + bf2f((u16)(pk[j] >> 16)) * crv[j]);
  *(u16x8*)&y[vi * 8] = o;
}

// ---------------------------------------------------------------------------
// head: out[t][o] = softplus(y1[t] . Wout[o] + bout[o]) + 1
// ---------------------------------------------------------------------------
__global__ __launch_bounds__(256) void head(
    const u16* __restrict__ y1, const float* __restrict__ Wout,
    const float* __restrict__ bout, float* __restrict__ out)
{
  __shared__ u16 ly[64 * 264];
  __shared__ float lw[4 * HID];
  __shared__ float lb[4];
  const int tid = threadIdx.x;
  for (int i = tid; i < 4 * HID; i += 256) lw[i] = Wout[i];
  if (tid < 4) lb[tid] = bout[tid];
  const size_t rbase = (size_t)blockIdx.x * 64 * HID;
#pragma unroll
  for (int i = 0; i < 8; ++i) {
    const int lin = i * 256 + tid;        // 2048 chunks of 8 bf16
    const int r = lin >> 5, c8 = lin & 31;
    *(u16x8*)&ly[r * 264 + c8 * 8] = *(const u16x8*)&y1[rbase + (size_t)r * HID + c8 * 8];
  }
  __syncthreads();
  const int t = tid >> 2, o = tid & 3;
  float acc = lb[o];
#pragma unroll 8
  for (int h = 0; h < HID; ++h)
    acc += bf2f(ly[t * 264 + h]) * lw[o * HID + h];
  out[((size_t)blockIdx.x * 64 + t) * 4 + o] = logf(1.f + __expf(acc)) + 1.f;
}

// ---------------------------------------------------------------------------
extern "C" void kernel_launch(void* const* d_in, const int* in_sizes, int n_in,
                              void* d_out, int out_size, void* d_ws, size_t ws_size,
                              hipStream_t stream)
{
  (void)in_sizes; (void)n_in; (void)out_size; (void)ws_size;
  const float* obs   = (const float*)d_in[0];
  const int*   act   = (const int*)d_in[1];
  const float* emb   = (const float*)d_in[2];
  const float* Win0  = (const float*)d_in[3];
  const float* WB0   = (const float*)d_in[4];
  const float* WC0   = (const float*)d_in[5];
  const float* Wd0   = (const float*)d_in[6];
  const float* Alog0 = (const float*)d_in[7];
  const float* Win1  = (const float*)d_in[8];
  const float* WB1   = (const float*)d_in[9];
  const float* WC1   = (const float*)d_in[10];
  const float* Wd1   = (const float*)d_in[11];
  const float* Alog1 = (const float*)d_in[12];
  const float* Wout  = (const float*)d_in[13];
  const float* bout  = (const float*)d_in[14];
  float* out = (float*)d_out;

  char* ws = (char*)d_ws;
  size_t off = 0;
  auto alloc = [&](size_t bytes) {
    char* p = ws + off;
    off += (bytes + 255) & ~(size_t)255;
    return p;
  };
  u16*      x0    = (u16*)     alloc((size_t)T_LEN * K0 * 2);   // 12.6 MB
  u16*      W0v   = (u16*)     alloc((size_t)1024 * K0 * 2);    // 0.2 MB
  u16*      W1v   = (u16*)     alloc((size_t)1024 * K1 * 2);    // 0.5 MB
  float*    Aneg  = (float*)   alloc(512 * 4);
  unsigned* uvb   = (unsigned*)alloc((size_t)T_LEN * HID * 4);  // 67 MB packed (u,v)
  u16*      y     = (u16*)     alloc((size_t)T_LEN * HID * 2);  // 33.5 MB (reused L0->L1)
  float*    aprod = (float*)   alloc((size_t)NCHUNK * HID * 4); // 1 MB
  float*    hlast = (float*)   alloc((size_t)NCHUNK * HID * 4); // 1 MB
  float*    clocal= (float*)   alloc((size_t)NCHUNK * HID * 4); // 1 MB
  float*    apfxc = (float*)   alloc((size_t)NCHUNK * HID * 4); // 1 MB
  float*    segAP = (float*)   alloc((size_t)NSEG * HID * 4);
  float*    segHL = (float*)   alloc((size_t)NSEG * HID * 4);
  float*    segc  = (float*)   alloc((size_t)NSEG * HID * 4);
  // total ~118 MB

  build_x0<<<T_LEN * 24 / 256, 256, 0, stream>>>(obs, act, emb, x0);
  prep_w<<<(1024 * K0 + 1024 * K1 + 512 + 255) / 256, 256, 0, stream>>>(
      Win0, WB0, WC0, Wd0, Alog0, Win1, WB1, WC1, Wd1, Alog1, W0v, W1v, Aneg);

  // layer 0
  gemm_scan<K0><<<4096, 256, 0, stream>>>(x0, W0v, Aneg, uvb, aprod, hlast);
  pass2a<<<NSEG, 256, 0, stream>>>(aprod, hlast, clocal, apfxc, segAP, segHL);
  pass2b<<<1, 256, 0, stream>>>(segAP, segHL, segc);
  combine<<<T_LEN * HID / 8 / 256, 256, 0, stream>>>(uvb, clocal, apfxc, segc, y);

  // layer 1
  gemm_scan<K1><<<4096, 256, 0, stream>>>(y, W1v, Aneg + 256, uvb, aprod, hlast);
  pass2a<<<NSEG, 256, 0, stream>>>(aprod, hlast, clocal, apfxc, segAP, segHL);
  pass2b<<<1, 256, 0, stream>>>(segAP, segHL, segc);
  combine<<<T_LEN * HID / 8 / 256, 256, 0, stream>>>(uvb, clocal, apfxc, segc, y);

  // output head
  head<<<T_LEN / 64, 256, 0, stream>>>(y, Wout, bout, out);
}